// Round 8
// baseline (524.497 us; speedup 1.0000x reference)
//
#include <hip/hip_runtime.h>
#include <hip/hip_bf16.h>
#include <math.h>

typedef __attribute__((ext_vector_type(8))) short short8;
typedef __attribute__((ext_vector_type(4))) float f32x4;

__device__ __forceinline__ float sigm(float v) { return 1.0f / (1.0f + expf(-v)); }
__device__ __forceinline__ unsigned short f2b(float f) {
  __hip_bfloat16 h = __float2bfloat16(f);
  return __builtin_bit_cast(unsigned short, h);
}
__device__ __forceinline__ void gload16(const void* g, void* l) {
  __builtin_amdgcn_global_load_lds(
      (const __attribute__((address_space(1))) unsigned int*)g,
      (__attribute__((address_space(3))) unsigned int*)l, 16, 0, 0);
}
__device__ __forceinline__ short8 pack8(float4 a, float4 b) {
  short8 r;
  r[0] = (short)f2b(a.x); r[1] = (short)f2b(a.y);
  r[2] = (short)f2b(a.z); r[3] = (short)f2b(a.w);
  r[4] = (short)f2b(b.x); r[5] = (short)f2b(b.y);
  r[6] = (short)f2b(b.z); r[7] = (short)f2b(b.w);
  return r;
}

// ---------------------------------------------------------------------------
// K0: pre-convert eW1[:, :2048] -> Wb1 bf16 [128][2048], dW4 -> Wb4 bf16 [2048][128]
// ---------------------------------------------------------------------------
__global__ __launch_bounds__(256) void wcvt_kernel(
    const float* __restrict__ eW1, const float* __restrict__ dW4,
    unsigned short* __restrict__ Wb1, unsigned short* __restrict__ Wb4)
{
  int idx = blockIdx.x * 256 + threadIdx.x;   // 0..262143
  int o = idx >> 11, k = idx & 2047;
  Wb1[idx] = f2b(eW1[(size_t)o * 2049 + k]);
  Wb4[idx] = f2b(dW4[idx]);
}

// ---------------------------------------------------------------------------
// K1: MFMA dual GEMM: accx = x@W.T, accd = xd@W.T (bf16 mfma, fp32 acc)
// v8: BM=64 (512 thr, 8 waves = 2 row-groups x 4 col-groups) halves W traffic;
// BK=32, 4 LDS buffers (96KB), depth-3 counted-vmcnt pipeline: per wave each
// STAGE = 3 global_load_lds -> steady-state vmcnt(9), tail 6/3/0.
// A 128B rows XOR (ln&7)<<4 (2-way, free); W 64B rows XOR (ln&3)<<4.
// ---------------------------------------------------------------------------
__global__ __launch_bounds__(512, 1) void enc1_mfma(
    const float* __restrict__ x, const float* __restrict__ xd,
    const float* __restrict__ tr, const unsigned short* __restrict__ Wb,
    const float* __restrict__ Wfull, const float* __restrict__ bias,
    float* __restrict__ a1, float* __restrict__ dz1)
{
  // per buffer (24KB): A f32[64][32] @0 (8KB), D @8192, W bf16[128][32] @16384 (8KB)
  __shared__ __align__(16) char sm[4 * 24576];
  const int t = threadIdx.x;
  const int w = t >> 6, L = t & 63, q = L >> 4, ln = L & 15;
  const int wr = w >> 2;       // row group 0..1 (32 rows each)
  const int wc = w & 3;        // col group 0..3 (32 cols each)
  const int r0 = blockIdx.x * 64;

  // staging source mappings (inverse of read-side XOR swizzle)
  const int arow = t >> 3;                               // 0..63
  const int acol = (((t & 7) ^ (arow & 7)) & 7) << 2;    // float offset in [0,32)
  const int wrow = t >> 2;                               // 0..127
  const int wcol = (((t & 3) ^ (wrow & 3)) & 3) << 3;    // short offset in [0,32)
  const float* xsrc = x  + (size_t)(r0 + arow) * 2048 + acol;
  const float* dsrc = xd + (size_t)(r0 + arow) * 2048 + acol;
  const unsigned short* wsrc = Wb + (size_t)wrow * 2048 + wcol;
  const int lb = w << 10;                                // wave-uniform LDS sub-base

#define STAGE(c, kt) { \
    const int kb = (kt) * 32; \
    char* b_ = sm + (c) * 24576; \
    gload16(xsrc + kb, b_ + lb); \
    gload16(dsrc + kb, b_ + 8192 + lb); \
    gload16(wsrc + kb, b_ + 16384 + lb); }

  f32x4 accx[2][2], accd[2][2];
#pragma unroll
  for (int m = 0; m < 2; ++m)
#pragma unroll
    for (int n = 0; n < 2; ++n) {
      accx[m][n] = (f32x4){0.f, 0.f, 0.f, 0.f};
      accd[m][n] = (f32x4){0.f, 0.f, 0.f, 0.f};
    }

  STAGE(0, 0)
  STAGE(1, 1)
  STAGE(2, 2)
  for (int kt = 0; kt < 64; ++kt) {
    if (kt < 61) {
      STAGE((kt + 3) & 3, kt + 3)
      asm volatile("s_waitcnt vmcnt(9)" ::: "memory");
    } else if (kt == 61) {
      asm volatile("s_waitcnt vmcnt(6)" ::: "memory");
    } else if (kt == 62) {
      asm volatile("s_waitcnt vmcnt(3)" ::: "memory");
    } else {
      asm volatile("s_waitcnt vmcnt(0)" ::: "memory");
    }
    __builtin_amdgcn_sched_barrier(0);
    __builtin_amdgcn_s_barrier();          // tile kt staged for all waves
    __builtin_amdgcn_sched_barrier(0);

    const char* bA = sm + (kt & 3) * 24576;
    const char* bD = bA + 8192;
    const char* bW = bA + 16384;
    short8 ax[2], ad[2], bw[2];
#pragma unroll
    for (int m = 0; m < 2; ++m) {
      const int row = wr * 32 + m * 16 + ln;
      const int key = (ln & 7) << 4;
      float4 lo  = *(const float4*)(bA + row * 128 + ((q * 32     ) ^ key));
      float4 hi  = *(const float4*)(bA + row * 128 + ((q * 32 + 16) ^ key));
      float4 dlo = *(const float4*)(bD + row * 128 + ((q * 32     ) ^ key));
      float4 dhi = *(const float4*)(bD + row * 128 + ((q * 32 + 16) ^ key));
      ax[m] = pack8(lo, hi);
      ad[m] = pack8(dlo, dhi);
    }
#pragma unroll
    for (int n = 0; n < 2; ++n) {
      const int row = wc * 32 + n * 16 + ln;
      bw[n] = *(const short8*)(bW + row * 64 + ((q * 16) ^ ((ln & 3) << 4)));
    }
#pragma unroll
    for (int m = 0; m < 2; ++m)
#pragma unroll
      for (int n = 0; n < 2; ++n) {
        accx[m][n] = __builtin_amdgcn_mfma_f32_16x16x32_bf16(ax[m], bw[n], accx[m][n], 0, 0, 0);
        accd[m][n] = __builtin_amdgcn_mfma_f32_16x16x32_bf16(ad[m], bw[n], accd[m][n], 0, 0, 0);
      }
    if (kt < 63) {
      // protect buffer (kt)&3 from restage at iteration kt+1; NO vmem drain
      asm volatile("s_waitcnt lgkmcnt(0)" ::: "memory");
      __builtin_amdgcn_sched_barrier(0);
      __builtin_amdgcn_s_barrier();
      __builtin_amdgcn_sched_barrier(0);
    }
  }
#undef STAGE

  // epilogue: C[row = wr*32 + m*16 + q*4 + r][col = wc*32 + n*16 + ln]
#pragma unroll
  for (int m = 0; m < 2; ++m) {
#pragma unroll
    for (int r = 0; r < 4; ++r) {
      const int row = r0 + wr * 32 + m * 16 + q * 4 + r;
      const float trv = tr[row];
#pragma unroll
      for (int n = 0; n < 2; ++n) {
        const int col = wc * 32 + n * 16 + ln;
        const float wl = Wfull[(size_t)col * 2049 + 2048];
        float p = accx[m][n][r] + trv * wl + bias[col];
        float g = accd[m][n][r] + trv * wl;
        float a = sigm(p);
        a1 [(size_t)row * 128 + col] = a;
        dz1[(size_t)row * 128 + col] = a * (1.f - a) * g;
      }
    }
  }
}

// ---------------------------------------------------------------------------
// K2: encoder layers 2-4 (unchanged).
// ---------------------------------------------------------------------------
__global__ __launch_bounds__(256) void enc_small_kernel(
    const float* __restrict__ a1, const float* __restrict__ dz1,
    const float* __restrict__ W2, const float* __restrict__ b2,
    const float* __restrict__ W3, const float* __restrict__ b3,
    const float* __restrict__ W4, const float* __restrict__ b4,
    const float* __restrict__ coef, const float* __restrict__ size_in,
    const float* __restrict__ treat,
    float* __restrict__ z_out, float* __restrict__ zdp_out,
    float* __restrict__ pe0, float* __restrict__ pe1, float* __restrict__ pe2)
{
  __shared__ float sW2[64 * 129];
  __shared__ float sW3[32 * 65];
  __shared__ float sW4[96];
  __shared__ float sB2[64], sB3[32], sB4[3], sC[21];
  __shared__ __align__(16) float a1s[16 * 128], d1s[16 * 128];
  __shared__ float a2s[16 * 64],  d2s[16 * 64];
  __shared__ float a3s[16 * 32],  d3s[16 * 32];
  __shared__ float zs[48], zds[48];
  __shared__ float rowl[16][3];
  const int t = threadIdx.x;
  for (int i = t; i < 64 * 128; i += 256) sW2[(i >> 7) * 129 + (i & 127)] = W2[i];
  for (int i = t; i < 32 * 64;  i += 256) sW3[(i >> 6) * 65  + (i & 63)]  = W3[i];
  if (t < 96) sW4[t] = W4[t];
  if (t < 64) sB2[t] = b2[t];
  if (t < 32) sB3[t] = b3[t];
  if (t < 3)  sB4[t] = b4[t];
  if (t < 21) sC[t]  = coef[t];
  const int r0 = blockIdx.x * 16;
  {
    const float4* a1g = (const float4*)(a1  + (size_t)r0 * 128);
    const float4* d1g = (const float4*)(dz1 + (size_t)r0 * 128);
    float4* a1s4 = (float4*)a1s;
    float4* d1s4 = (float4*)d1s;
#pragma unroll
    for (int i = 0; i < 2; ++i) {
      a1s4[t + i * 256] = a1g[t + i * 256];
      d1s4[t + i * 256] = d1g[t + i * 256];
    }
  }
  __syncthreads();
  {
    const int o = t & 63, rb = t >> 6;
    float p[4] = {0.f, 0.f, 0.f, 0.f}, g[4] = {0.f, 0.f, 0.f, 0.f};
#pragma unroll 4
    for (int k = 0; k < 128; ++k) {
      const float wv = sW2[o * 129 + k];
#pragma unroll
      for (int u = 0; u < 4; ++u) {
        p[u] = fmaf(wv, a1s[(rb + u * 4) * 128 + k], p[u]);
        g[u] = fmaf(wv, d1s[(rb + u * 4) * 128 + k], g[u]);
      }
    }
#pragma unroll
    for (int u = 0; u < 4; ++u) {
      float a = sigm(p[u] + sB2[o]);
      a2s[(rb + u * 4) * 64 + o] = a;
      d2s[(rb + u * 4) * 64 + o] = a * (1.f - a) * g[u];
    }
  }
  __syncthreads();
  {
    const int o = t & 31, r3 = t >> 5;
    float p[2] = {0.f, 0.f}, g[2] = {0.f, 0.f};
#pragma unroll 4
    for (int k = 0; k < 64; ++k) {
      const float wv = sW3[o * 65 + k];
#pragma unroll
      for (int u = 0; u < 2; ++u) {
        p[u] = fmaf(wv, a2s[(r3 + u * 8) * 64 + k], p[u]);
        g[u] = fmaf(wv, d2s[(r3 + u * 8) * 64 + k], g[u]);
      }
    }
#pragma unroll
    for (int u = 0; u < 2; ++u) {
      float a = sigm(p[u] + sB3[o]);
      a3s[(r3 + u * 8) * 32 + o] = a;
      d3s[(r3 + u * 8) * 32 + o] = a * (1.f - a) * g[u];
    }
  }
  __syncthreads();
  if (t < 48) {
    const int r = t / 3, j = t % 3;
    float p = 0.f, g = 0.f;
#pragma unroll
    for (int k = 0; k < 32; ++k) {
      float wv = sW4[j * 32 + k];
      p = fmaf(wv, a3s[r * 32 + k], p);
      g = fmaf(wv, d3s[r * 32 + k], g);
    }
    float zv = p + sB4[j];
    zs [r * 3 + j] = zv;
    zds[r * 3 + j] = g;
    z_out[(size_t)(r0 + r) * 3 + j] = zv;
  }
  __syncthreads();
  if (t < 16) {
    const int r = t;
    float s = zs[r * 3 + 0], d = zs[r * 3 + 1], tt = zs[r * 3 + 2];
    float th[7] = {1.f, s, s * s, s * d, s * tt, s * s * d, s * s * tt};
    float sz = 0.f;
    for (int j = 0; j < 3; ++j) {
      float zp = 0.f;
#pragma unroll
      for (int i = 0; i < 7; ++i) zp = fmaf(th[i], sC[i * 3 + j], zp);
      zdp_out[(size_t)(r0 + r) * 3 + j] = zp;
      float e = zds[r * 3 + j] - zp;
      sz += e * e;
    }
    float e0 = s - size_in[r0 + r];
    float logit = tt;
    float trv = treat[r0 + r];
    float lt = fmaxf(logit, 0.f) + log1pf(expf(-fabsf(logit))) - logit * trv;
    rowl[r][0] = e0 * e0; rowl[r][1] = lt; rowl[r][2] = sz;
  }
  __syncthreads();
  if (t == 0) {
    float s0 = 0, s1 = 0, s2 = 0;
    for (int r = 0; r < 16; ++r) { s0 += rowl[r][0]; s1 += rowl[r][1]; s2 += rowl[r][2]; }
    pe0[blockIdx.x] = s0;
    pe1[blockIdx.x] = s1;
    pe2[blockIdx.x] = s2;
  }
}

// ---------------------------------------------------------------------------
// K3: decoder layers 1-3 (unchanged).
// ---------------------------------------------------------------------------
__global__ __launch_bounds__(256) void dec_small_kernel(
    const float* __restrict__ z_in, const float* __restrict__ zdp,
    const float* __restrict__ W1, const float* __restrict__ b1,
    const float* __restrict__ W2, const float* __restrict__ b2,
    const float* __restrict__ W3, const float* __restrict__ b3,
    unsigned short* __restrict__ h3b, unsigned short* __restrict__ g3b)
{
  __shared__ float sW1[96], sB1[32];
  __shared__ float sW2[64 * 33], sB2[64];
  __shared__ float sW3[128 * 65], sB3[128];
  __shared__ float zr[48], zp[48];
  __shared__ float h1s[16 * 32], g1s[16 * 32];
  __shared__ float h2s[16 * 64], g2s[16 * 64];
  const int t = threadIdx.x;
  for (int i = t; i < 64 * 32;  i += 256) sW2[(i >> 5) * 33 + (i & 31)] = W2[i];
  for (int i = t; i < 128 * 64; i += 256) sW3[(i >> 6) * 65 + (i & 63)] = W3[i];
  if (t < 96)  sW1[t] = W1[t];
  if (t < 32)  sB1[t] = b1[t];
  if (t < 64)  sB2[t] = b2[t];
  if (t < 128) sB3[t] = b3[t];
  const int r0 = blockIdx.x * 16;
  if (t < 48) { zr[t] = z_in[(size_t)r0 * 3 + t]; zp[t] = zdp[(size_t)r0 * 3 + t]; }
  __syncthreads();
  {
    const int o = t & 31, rb = t >> 5;
    float p[2], g[2];
#pragma unroll
    for (int u = 0; u < 2; ++u) {
      const int r = rb + u * 8;
      float pp = sB1[o], gg = 0.f;
#pragma unroll
      for (int k = 0; k < 3; ++k) {
        float wv = sW1[o * 3 + k];
        pp = fmaf(wv, zr[r * 3 + k], pp);
        gg = fmaf(wv, zp[r * 3 + k], gg);
      }
      p[u] = pp; g[u] = gg;
    }
#pragma unroll
    for (int u = 0; u < 2; ++u) {
      const int r = rb + u * 8;
      float h = sigm(p[u]);
      h1s[r * 32 + o] = h; g1s[r * 32 + o] = h * (1.f - h) * g[u];
    }
  }
  __syncthreads();
  {
    const int o = t & 63, rb = t >> 6;
    float p[4], g[4];
#pragma unroll
    for (int u = 0; u < 4; ++u) { p[u] = sB2[o]; g[u] = 0.f; }
#pragma unroll 4
    for (int k = 0; k < 32; ++k) {
      const float wv = sW2[o * 33 + k];
#pragma unroll
      for (int u = 0; u < 4; ++u) {
        p[u] = fmaf(wv, h1s[(rb + u * 4) * 32 + k], p[u]);
        g[u] = fmaf(wv, g1s[(rb + u * 4) * 32 + k], g[u]);
      }
    }
#pragma unroll
    for (int u = 0; u < 4; ++u) {
      float h = sigm(p[u]);
      h2s[(rb + u * 4) * 64 + o] = h;
      g2s[(rb + u * 4) * 64 + o] = h * (1.f - h) * g[u];
    }
  }
  __syncthreads();
  {
    const int o = t & 127, rb2 = t >> 7;
    float p[8], g[8];
#pragma unroll
    for (int u = 0; u < 8; ++u) { p[u] = sB3[o]; g[u] = 0.f; }
#pragma unroll 4
    for (int k = 0; k < 64; ++k) {
      const float wv = sW3[o * 65 + k];
#pragma unroll
      for (int u = 0; u < 8; ++u) {
        p[u] = fmaf(wv, h2s[(rb2 + u * 2) * 64 + k], p[u]);
        g[u] = fmaf(wv, g2s[(rb2 + u * 2) * 64 + k], g[u]);
      }
    }
#pragma unroll
    for (int u = 0; u < 8; ++u) {
      const int r = rb2 + u * 2;
      float h = sigm(p[u]);
      h3b[(size_t)(r0 + r) * 128 + o] = f2b(h);
      g3b[(size_t)(r0 + r) * 128 + o] = f2b(h * (1.f - h) * g[u]);
    }
  }
}

// ---------------------------------------------------------------------------
// K4: dec4 (unchanged from r6/r7).
// ---------------------------------------------------------------------------
__global__ __launch_bounds__(256, 2) void dec4_mfma(
    const unsigned short* __restrict__ h3b, const unsigned short* __restrict__ g3b,
    const unsigned short* __restrict__ Wb, const float* __restrict__ bias,
    const float* __restrict__ x, const float* __restrict__ xd,
    float* __restrict__ xhat, float* __restrict__ pr, float* __restrict__ ps)
{
  __shared__ __align__(16) char Wsm[2][16384];   // K-half W tiles (dbuf)
  __shared__ float sH[32 * 132];
  __shared__ float sG[32 * 132];
  __shared__ float red[8];
  const int t = threadIdx.x, w = t >> 6, L = t & 63, q = L >> 4, ln = L & 15;
  const int r0 = blockIdx.x * 32;

  short8 fh[2][4], fg[2][4];
  {
    const size_t a0 = (size_t)(r0 + ln) * 128;
    const size_t a1 = (size_t)(r0 + 16 + ln) * 128;
#pragma unroll
    for (int ks = 0; ks < 4; ++ks) {
      const int kb = ks * 32 + q * 8;
      fh[0][ks] = *(const short8*)&h3b[a0 + kb];
      fh[1][ks] = *(const short8*)&h3b[a1 + kb];
      fg[0][ks] = *(const short8*)&g3b[a0 + kb];
      fg[1][ks] = *(const short8*)&g3b[a1 + kb];
    }
  }

  const int srow0 = t >> 3;
  const int sch   = t & 7;
#define WSTAGE(buf, c_, kh_) { \
    char* dst = Wsm[buf] + (w << 10); \
    _Pragma("unroll") \
    for (int i = 0; i < 4; ++i) { \
      const int row_ = i * 32 + srow0; \
      const unsigned short* src_ = Wb + (((size_t)(c_) * 128 + row_) << 7) + (kh_) * 64 + ((sch ^ (row_ & 7)) << 3); \
      gload16(src_, dst + i * 4096); \
    } }

#define WFRAG(buf, ksl, n_) \
    (*(const short8*)(Wsm[buf] + ((w * 32 + (n_) * 16 + ln) << 7) + ((((ksl) * 4 + q) ^ (ln & 7)) << 4)))

  f32x4 accH[2][2], accG[2][2];
  const int erow = t >> 3;
  const int colb = (t & 7) * 4;
  const size_t ebase0 = (size_t)(r0 + erow) * 2048 + colb;

  WSTAGE(0, 0, 0)
  WSTAGE(1, 0, 1)
  float4 exC[4], edC[4], exN[4], edN[4];
#pragma unroll
  for (int j = 0; j < 4; ++j) {
    exC[j] = *(const float4*)&x [ebase0 + j * 32];
    edC[j] = *(const float4*)&xd[ebase0 + j * 32];
  }
  __syncthreads();

  float rsum = 0.f, ssum = 0.f;
  for (int c = 0; c < 16; ++c) {
#pragma unroll
    for (int m = 0; m < 2; ++m)
#pragma unroll
      for (int n = 0; n < 2; ++n) {
        accH[m][n] = (f32x4){0.f, 0.f, 0.f, 0.f};
        accG[m][n] = (f32x4){0.f, 0.f, 0.f, 0.f};
      }
#pragma unroll
    for (int ksl = 0; ksl < 2; ++ksl) {
      short8 bw0 = WFRAG(0, ksl, 0);
      short8 bw1 = WFRAG(0, ksl, 1);
      accH[0][0] = __builtin_amdgcn_mfma_f32_16x16x32_bf16(fh[0][ksl], bw0, accH[0][0], 0, 0, 0);
      accH[0][1] = __builtin_amdgcn_mfma_f32_16x16x32_bf16(fh[0][ksl], bw1, accH[0][1], 0, 0, 0);
      accH[1][0] = __builtin_amdgcn_mfma_f32_16x16x32_bf16(fh[1][ksl], bw0, accH[1][0], 0, 0, 0);
      accH[1][1] = __builtin_amdgcn_mfma_f32_16x16x32_bf16(fh[1][ksl], bw1, accH[1][1], 0, 0, 0);
      accG[0][0] = __builtin_amdgcn_mfma_f32_16x16x32_bf16(fg[0][ksl], bw0, accG[0][0], 0, 0, 0);
      accG[0][1] = __builtin_amdgcn_mfma_f32_16x16x32_bf16(fg[0][ksl], bw1, accG[0][1], 0, 0, 0);
      accG[1][0] = __builtin_amdgcn_mfma_f32_16x16x32_bf16(fg[1][ksl], bw0, accG[1][0], 0, 0, 0);
      accG[1][1] = __builtin_amdgcn_mfma_f32_16x16x32_bf16(fg[1][ksl], bw1, accG[1][1], 0, 0, 0);
    }
    __syncthreads();
    if (c < 15) {
      WSTAGE(0, c + 1, 0)
#pragma unroll
      for (int j = 0; j < 4; ++j) {
        exN[j] = *(const float4*)&x [ebase0 + (c + 1) * 128 + j * 32];
        edN[j] = *(const float4*)&xd[ebase0 + (c + 1) * 128 + j * 32];
      }
    }
#pragma unroll
    for (int ksl = 0; ksl < 2; ++ksl) {
      short8 bw0 = WFRAG(1, ksl, 0);
      short8 bw1 = WFRAG(1, ksl, 1);
      accH[0][0] = __builtin_amdgcn_mfma_f32_16x16x32_bf16(fh[0][2 + ksl], bw0, accH[0][0], 0, 0, 0);
      accH[0][1] = __builtin_amdgcn_mfma_f32_16x16x32_bf16(fh[0][2 + ksl], bw1, accH[0][1], 0, 0, 0);
      accH[1][0] = __builtin_amdgcn_mfma_f32_16x16x32_bf16(fh[1][2 + ksl], bw0, accH[1][0], 0, 0, 0);
      accH[1][1] = __builtin_amdgcn_mfma_f32_16x16x32_bf16(fh[1][2 + ksl], bw1, accH[1][1], 0, 0, 0);
      accG[0][0] = __builtin_amdgcn_mfma_f32_16x16x32_bf16(fg[0][2 + ksl], bw0, accG[0][0], 0, 0, 0);
      accG[0][1] = __builtin_amdgcn_mfma_f32_16x16x32_bf16(fg[0][2 + ksl], bw1, accG[0][1], 0, 0, 0);
      accG[1][0] = __builtin_amdgcn_mfma_f32_16x16x32_bf16(fg[1][2 + ksl], bw0, accG[1][0], 0, 0, 0);
      accG[1][1] = __builtin_amdgcn_mfma_f32_16x16x32_bf16(fg[1][2 + ksl], bw1, accG[1][1], 0, 0, 0);
    }
#pragma unroll
    for (int m = 0; m < 2; ++m)
#pragma unroll
      for (int n = 0; n < 2; ++n)
#pragma unroll
        for (int r = 0; r < 4; ++r) {
          const int rr = m * 16 + q * 4 + r;
          const int cc = w * 32 + n * 16 + ln;
          sH[rr * 132 + cc] = accH[m][n][r];
          sG[rr * 132 + cc] = accG[m][n][r];
        }
    __syncthreads();
    if (c < 15) WSTAGE(1, c + 1, 1)
    {
      const size_t gb = ebase0 + (size_t)c * 128;
#pragma unroll
      for (int j = 0; j < 4; ++j) {
        const int cc = colb + j * 32;
        float4 hv = *(const float4*)&sH[erow * 132 + cc];
        float4 gv = *(const float4*)&sG[erow * 132 + cc];
        float4 bv = *(const float4*)&bias[c * 128 + cc];
        f32x4 xh = {hv.x + bv.x, hv.y + bv.y, hv.z + bv.z, hv.w + bv.w};
        __builtin_nontemporal_store(xh, (f32x4*)&xhat[gb + j * 32]);
        float e;
        e = exC[j].x - xh[0]; rsum = fmaf(e, e, rsum);
        e = exC[j].y - xh[1]; rsum = fmaf(e, e, rsum);
        e = exC[j].z - xh[2]; rsum = fmaf(e, e, rsum);
        e = exC[j].w - xh[3]; rsum = fmaf(e, e, rsum);
        e = edC[j].x - gv.x; ssum = fmaf(e, e, ssum);
        e = edC[j].y - gv.y; ssum = fmaf(e, e, ssum);
        e = edC[j].z - gv.z; ssum = fmaf(e, e, ssum);
        e = edC[j].w - gv.w; ssum = fmaf(e, e, ssum);
      }
    }
#pragma unroll
    for (int j = 0; j < 4; ++j) { exC[j] = exN[j]; edC[j] = edN[j]; }
    __syncthreads();
  }
#undef WSTAGE
#undef WFRAG

#pragma unroll
  for (int off = 32; off > 0; off >>= 1) {
    rsum += __shfl_down(rsum, off);
    ssum += __shfl_down(ssum, off);
  }
  if (L == 0) { red[w * 2] = rsum; red[w * 2 + 1] = ssum; }
  __syncthreads();
  if (t == 0) {
    pr[blockIdx.x] = red[0] + red[2] + red[4] + red[6];
    ps[blockIdx.x] = red[1] + red[3] + red[5] + red[7];
  }
}

// ---------------------------------------------------------------------------
// K5: reduce all partials + write the 6 scalar outputs (unchanged).
// ---------------------------------------------------------------------------
__global__ __launch_bounds__(256) void finalize_kernel(
    const float* __restrict__ pr, const float* __restrict__ ps,
    const float* __restrict__ pe0, const float* __restrict__ pe1,
    const float* __restrict__ pe2, const float* __restrict__ coef,
    float* __restrict__ outp)
{
  __shared__ float sred[4][5];
  const int t = threadIdx.x, L = t & 63, w = t >> 6;
  float s[5] = {0.f, 0.f, 0.f, 0.f, 0.f};
  if (t < 128) {                           // pr/ps: 512 floats each
    float4 a = *(const float4*)&pr[t * 4];
    float4 b = *(const float4*)&ps[t * 4];
    s[0] += a.x + a.y + a.z + a.w;
    s[1] += b.x + b.y + b.z + b.w;
  }
  if (t < 256) {                           // pe*: 1024 floats each
    float4 a = *(const float4*)&pe0[t * 4];
    float4 b = *(const float4*)&pe1[t * 4];
    float4 c = *(const float4*)&pe2[t * 4];
    s[2] += a.x + a.y + a.z + a.w;
    s[3] += b.x + b.y + b.z + b.w;
    s[4] += c.x + c.y + c.z + c.w;
  }
#pragma unroll
  for (int off = 32; off > 0; off >>= 1)
#pragma unroll
    for (int k = 0; k < 5; ++k) s[k] += __shfl_down(s[k], off);
  if (L == 0)
#pragma unroll
    for (int k = 0; k < 5; ++k) sred[w][k] = s[k];
  __syncthreads();
  if (t == 0) {
    float r[5];
#pragma unroll
    for (int k = 0; k < 5; ++k)
      r[k] = sred[0][k] + sred[1][k] + sred[2][k] + sred[3][k];
    outp[0] = r[2] * (1.0f / 16384.0f);      // loss_po
    outp[1] = r[3] * (1.0f / 16384.0f);      // loss_tr
    outp[2] = r[0] * (1.0f / 33554432.0f);   // recon
    outp[3] = r[1] * (1.0f / 33554432.0f);   // sindy_x
    outp[4] = r[4] * (1.0f / 49152.0f);      // sindy_z
    float l1 = 0.f;
    for (int i = 0; i < 21; ++i) l1 += fabsf(coef[i]);
    outp[5] = l1 * (1.0f / 21.0f);
  }
}

extern "C" void kernel_launch(void* const* d_in, const int* in_sizes, int n_in,
                              void* d_out, int out_size, void* d_ws, size_t ws_size,
                              hipStream_t stream) {
  (void)in_sizes; (void)n_in; (void)out_size; (void)ws_size;
  const float* x    = (const float*)d_in[0];
  const float* xd   = (const float*)d_in[1];
  const float* tr   = (const float*)d_in[2];
  const float* sz   = (const float*)d_in[3];
  const float* eW1  = (const float*)d_in[4];
  const float* eb1  = (const float*)d_in[5];
  const float* eW2  = (const float*)d_in[6];
  const float* eb2  = (const float*)d_in[7];
  const float* eW3  = (const float*)d_in[8];
  const float* eb3  = (const float*)d_in[9];
  const float* eW4  = (const float*)d_in[10];
  const float* eb4  = (const float*)d_in[11];
  const float* dW1  = (const float*)d_in[12];
  const float* db1  = (const float*)d_in[13];
  const float* dW2  = (const float*)d_in[14];
  const float* db2  = (const float*)d_in[15];
  const float* dW3  = (const float*)d_in[16];
  const float* db3  = (const float*)d_in[17];
  const float* dW4  = (const float*)d_in[18];
  const float* db4  = (const float*)d_in[19];
  const float* coef = (const float*)d_in[20];

  float* ws = (float*)d_ws;
  float* a1   = ws;                                       // 2097152 f32
  float* dz1  = ws + 2097152;                             // 2097152 f32
  float* zdp  = ws + 4194304;                             // 49152 f32
  unsigned short* h3b = (unsigned short*)(ws + 4243472);  // 2097152 bf16
  unsigned short* g3b = (unsigned short*)(ws + 5292048);  // 2097152 bf16
  unsigned short* Wb1 = (unsigned short*)(ws + 6340624);  // 262144 bf16
  unsigned short* Wb4 = (unsigned short*)(ws + 6471696);  // 262144 bf16
  // partial-sum arrays alias the Wb1 region (dead after enc1_mfma)
  float* pr  = ws + 6340624;                              // 512 f32
  float* ps  = ws + 6348816;                              // 512 f32
  float* pe0 = ws + 6357008;                              // 1024 f32
  float* pe1 = ws + 6361104;                              // 1024 f32
  float* pe2 = ws + 6365200;                              // 1024 f32

  float* z_out = (float*)d_out;                           // 16384*3
  float* xhat  = (float*)d_out + 49152;                   // 16384*2048
  float* scal  = (float*)d_out + 49152 + 33554432;        // 6 scalars

  wcvt_kernel<<<1024, 256, 0, stream>>>(eW1, dW4, Wb1, Wb4);
  enc1_mfma<<<256, 512, 0, stream>>>(x, xd, tr, Wb1, eW1, eb1, a1, dz1);
  enc_small_kernel<<<1024, 256, 0, stream>>>(a1, dz1, eW2, eb2, eW3, eb3, eW4, eb4,
                                             coef, sz, tr, z_out, zdp, pe0, pe1, pe2);
  dec_small_kernel<<<1024, 256, 0, stream>>>(z_out, zdp, dW1, db1, dW2, db2, dW3, db3,
                                             h3b, g3b);
  dec4_mfma<<<512, 256, 0, stream>>>(h3b, g3b, Wb4, db4, x, xd, xhat, pr, ps);
  finalize_kernel<<<1, 256, 0, stream>>>(pr, ps, pe0, pe1, pe2, coef, scal);
}

// Round 9
// 488.309 us; speedup vs baseline: 1.0741x; 1.0741x over previous
//
#include <hip/hip_runtime.h>
#include <hip/hip_bf16.h>
#include <math.h>

typedef __attribute__((ext_vector_type(8))) short short8;
typedef __attribute__((ext_vector_type(4))) float f32x4;

__device__ __forceinline__ float sigm(float v) { return 1.0f / (1.0f + expf(-v)); }
__device__ __forceinline__ unsigned short f2b(float f) {
  __hip_bfloat16 h = __float2bfloat16(f);
  return __builtin_bit_cast(unsigned short, h);
}
__device__ __forceinline__ void gload16(const void* g, void* l) {
  __builtin_amdgcn_global_load_lds(
      (const __attribute__((address_space(1))) unsigned int*)g,
      (__attribute__((address_space(3))) unsigned int*)l, 16, 0, 0);
}
__device__ __forceinline__ short8 pack8(float4 a, float4 b) {
  short8 r;
  r[0] = (short)f2b(a.x); r[1] = (short)f2b(a.y);
  r[2] = (short)f2b(a.z); r[3] = (short)f2b(a.w);
  r[4] = (short)f2b(b.x); r[5] = (short)f2b(b.y);
  r[6] = (short)f2b(b.z); r[7] = (short)f2b(b.w);
  return r;
}

// ---------------------------------------------------------------------------
// K0: pre-convert eW1[:, :2048] -> Wb1 bf16 [128][2048], dW4 -> Wb4 bf16 [2048][128]
// ---------------------------------------------------------------------------
__global__ __launch_bounds__(256) void wcvt_kernel(
    const float* __restrict__ eW1, const float* __restrict__ dW4,
    unsigned short* __restrict__ Wb1, unsigned short* __restrict__ Wb4)
{
  int idx = blockIdx.x * 256 + threadIdx.x;   // 0..262143
  int o = idx >> 11, k = idx & 2047;
  Wb1[idx] = f2b(eW1[(size_t)o * 2049 + k]);
  Wb4[idx] = f2b(dW4[idx]);
}

// ---------------------------------------------------------------------------
// K1 (fused): enc1 MFMA GEMM (BM=64, BK=64, r7-proven swizzles, counted vmcnt)
// + enc layers 2-4 + z/losses + dec layers 1-3 -> h3b/g3b. 512 thr, 64 rows,
// grid 256 (1 block/CU). LDS arena phase-aliased (~136 KB).
// ---------------------------------------------------------------------------
// LDS arena offsets (bytes)
#define A1S_OFF   0        // f32[64][128]   (phase B in)
#define D1S_OFF   32768    // f32[64][128]
#define W2S_OFF   65536    // f32[64][132]
#define A2S_OFF   99328    // f32[64][68]
#define D2S_OFF   116736   // f32[64][68]    -> end 134144
// after phase B (a1s/d1s/W2s dead):
#define W3S_OFF   0        // f32[32][68]
#define W2D_OFF   8704     // f32[64][36]
#define A3S_OFF   17920    // f32[64][36]
#define D3S_OFF   32768    // f32[64][36]
#define H1S_OFF   41984    // f32[64][36]
#define G1S_OFF   51200    // f32[64][36]
// after phase C (W2s/a2s dead):
#define W3D_OFF   65536    // f32[128][68]  -> 100352
#define H2S_OFF   100352   // f32[64][68]
#define G2S_OFF   117760   // f32[64][68]   -> 135168
// smalls
#define SB2_OFF   135168
#define SB3_OFF   135424
#define SB4_OFF   135552
#define SC_OFF    135568
#define W4S_OFF   135664
#define ZW1_OFF   136048
#define SB1D_OFF  136432
#define SB2D_OFF  136560
#define SB3D_OFF  136816
#define ZS_OFF    137328
#define ZDS_OFF   138096
#define ZP_OFF    138864
#define ARENA_SZ  139648

__global__ __launch_bounds__(512, 1) void fused_enc(
    const float* __restrict__ x, const float* __restrict__ xd,
    const float* __restrict__ tr, const unsigned short* __restrict__ Wb,
    const float* __restrict__ Wfull, const float* __restrict__ eb1,
    const float* __restrict__ W2, const float* __restrict__ b2,
    const float* __restrict__ W3, const float* __restrict__ b3,
    const float* __restrict__ W4, const float* __restrict__ b4,
    const float* __restrict__ coef, const float* __restrict__ size_in,
    const float* __restrict__ dW1, const float* __restrict__ db1,
    const float* __restrict__ dW2, const float* __restrict__ db2,
    const float* __restrict__ dW3, const float* __restrict__ db3,
    float* __restrict__ z_out,
    unsigned short* __restrict__ h3b, unsigned short* __restrict__ g3b,
    float* __restrict__ pe0, float* __restrict__ pe1, float* __restrict__ pe2)
{
  __shared__ __align__(16) char sm[ARENA_SZ];
  const int t = threadIdx.x;
  const int w = t >> 6, L = t & 63, q = L >> 4, ln = L & 15;
  const int wr = w >> 2, wc = w & 3;
  const int r0 = blockIdx.x * 64;

  // ---- GEMM staging source addresses (inverse of read-side XOR swizzle) ----
  const int c0r = t >> 4;                          // 0..31
  const int ajx = (((t & 15) ^ (c0r & 15)) & 15) << 2;
  const float* xsrc0 = x  + (size_t)(r0 + c0r) * 2048 + ajx;
  const float* xsrc1 = xsrc0 + 32 * 2048;
  const float* dsrc0 = xd + (size_t)(r0 + c0r) * 2048 + ajx;
  const float* dsrc1 = dsrc0 + 32 * 2048;
  const int w0r = t >> 3;                          // 0..63
  const int wjx = (((t & 7) ^ (w0r & 7)) & 7) << 3;
  const unsigned short* wsrc0 = Wb + (size_t)w0r * 2048 + wjx;
  const unsigned short* wsrc1 = wsrc0 + 64 * 2048;
  const int lb = w << 10;

#define STAGE(c, kt) { \
    const int kb = (kt) * 64; \
    char* b_ = sm + (c) * 49152; \
    gload16(xsrc0 + kb, b_ + lb); \
    gload16(xsrc1 + kb, b_ + 8192 + lb); \
    gload16(dsrc0 + kb, b_ + 16384 + lb); \
    gload16(dsrc1 + kb, b_ + 24576 + lb); \
    gload16(wsrc0 + kb, b_ + 32768 + lb); \
    gload16(wsrc1 + kb, b_ + 40960 + lb); }

  f32x4 accx[2][2], accd[2][2];
#pragma unroll
  for (int m = 0; m < 2; ++m)
#pragma unroll
    for (int n = 0; n < 2; ++n) {
      accx[m][n] = (f32x4){0.f, 0.f, 0.f, 0.f};
      accd[m][n] = (f32x4){0.f, 0.f, 0.f, 0.f};
    }

  STAGE(0, 0)
  for (int kt = 0; kt < 32; ++kt) {
    if (kt + 1 < 32) {
      STAGE((kt + 1) & 1, kt + 1)
      asm volatile("s_waitcnt vmcnt(6)" ::: "memory");
    } else {
      asm volatile("s_waitcnt vmcnt(0)" ::: "memory");
    }
    __builtin_amdgcn_sched_barrier(0);
    __builtin_amdgcn_s_barrier();
    __builtin_amdgcn_sched_barrier(0);

    const char* bA = sm + (kt & 1) * 49152;
    const char* bD = bA + 16384;
    const char* bW = bA + 32768;
#pragma unroll
    for (int ks = 0; ks < 2; ++ks) {
      short8 ax[2], ad[2], bwv[2];
#pragma unroll
      for (int m = 0; m < 2; ++m) {
        const int row = wr * 32 + m * 16 + ln;
        const int off = ks * 128 + q * 32;
        const int key = ln << 4;
        float4 lo  = *(const float4*)(bA + row * 256 + ((off     ) ^ key));
        float4 hi  = *(const float4*)(bA + row * 256 + ((off + 16) ^ key));
        float4 dlo = *(const float4*)(bD + row * 256 + ((off     ) ^ key));
        float4 dhi = *(const float4*)(bD + row * 256 + ((off + 16) ^ key));
        ax[m] = pack8(lo, hi);
        ad[m] = pack8(dlo, dhi);
      }
#pragma unroll
      for (int n = 0; n < 2; ++n) {
        const int row = wc * 32 + n * 16 + ln;
        bwv[n] = *(const short8*)(bW + row * 128 + ((ks * 64 + q * 16) ^ ((ln & 7) << 4)));
      }
#pragma unroll
      for (int m = 0; m < 2; ++m)
#pragma unroll
        for (int n = 0; n < 2; ++n) {
          accx[m][n] = __builtin_amdgcn_mfma_f32_16x16x32_bf16(ax[m], bwv[n], accx[m][n], 0, 0, 0);
          accd[m][n] = __builtin_amdgcn_mfma_f32_16x16x32_bf16(ad[m], bwv[n], accd[m][n], 0, 0, 0);
        }
    }
    if (kt + 1 < 32) {
      asm volatile("s_waitcnt lgkmcnt(0)" ::: "memory");
      __builtin_amdgcn_sched_barrier(0);
      __builtin_amdgcn_s_barrier();
      __builtin_amdgcn_sched_barrier(0);
    }
  }
#undef STAGE
  __syncthreads();   // GEMM buffers dead; arena reuse begins

  // ---- epilogue -> a1s/d1s in LDS; stage W2 + all small weights ----
  float* a1s = (float*)(sm + A1S_OFF);
  float* d1s = (float*)(sm + D1S_OFF);
  float* W2s = (float*)(sm + W2S_OFF);
  float* sB2 = (float*)(sm + SB2_OFF);
  float* sB3 = (float*)(sm + SB3_OFF);
  float* sB4 = (float*)(sm + SB4_OFF);
  float* sC  = (float*)(sm + SC_OFF);
  float* W4s = (float*)(sm + W4S_OFF);
  float* zW1 = (float*)(sm + ZW1_OFF);
  float* sB1d = (float*)(sm + SB1D_OFF);
  float* sB2d = (float*)(sm + SB2D_OFF);
  float* sB3d = (float*)(sm + SB3D_OFF);
  float* zs  = (float*)(sm + ZS_OFF);
  float* zds = (float*)(sm + ZDS_OFF);
  float* zp  = (float*)(sm + ZP_OFF);

#pragma unroll
  for (int m = 0; m < 2; ++m) {
#pragma unroll
    for (int r = 0; r < 4; ++r) {
      const int row = wr * 32 + m * 16 + q * 4 + r;
      const float trv = tr[r0 + row];
#pragma unroll
      for (int n = 0; n < 2; ++n) {
        const int col = wc * 32 + n * 16 + ln;
        const float wl = Wfull[(size_t)col * 2049 + 2048];
        float p = accx[m][n][r] + trv * wl + eb1[col];
        float g = accd[m][n][r] + trv * wl;
        float a = sigm(p);
        a1s[row * 128 + col] = a;
        d1s[row * 128 + col] = a * (1.f - a) * g;
      }
    }
  }
  for (int i = t; i < 8192; i += 512) W2s[(i >> 7) * 132 + (i & 127)] = W2[i];
  if (t < 64)  sB2[t] = b2[t];
  if (t < 32)  sB3[t] = b3[t];
  if (t < 3)   sB4[t] = b4[t];
  if (t < 21)  sC[t]  = coef[t];
  if (t < 96)  W4s[t] = W4[t];
  if (t < 96)  zW1[t] = dW1[t];
  if (t < 32)  sB1d[t] = db1[t];
  if (t < 64)  sB2d[t] = db2[t];
  if (t < 128) sB3d[t] = db3[t];
  __syncthreads();

  // ---- Phase B: enc layer 2 (64 outs, k=128) ----
  {
    const int o = t & 63, w8 = t >> 6;   // rows w8 + u*8
    const float4* W2f = (const float4*)W2s;
    const float4* a1f = (const float4*)a1s;
    const float4* d1f = (const float4*)d1s;
    float p[8], g[8];
#pragma unroll
    for (int u = 0; u < 8; ++u) { p[u] = 0.f; g[u] = 0.f; }
    for (int k4 = 0; k4 < 32; ++k4) {
      float4 wv = W2f[o * 33 + k4];
#pragma unroll
      for (int u = 0; u < 8; ++u) {
        float4 av = a1f[(w8 + u * 8) * 32 + k4];
        float4 dv = d1f[(w8 + u * 8) * 32 + k4];
        p[u] = fmaf(wv.x, av.x, fmaf(wv.y, av.y, fmaf(wv.z, av.z, fmaf(wv.w, av.w, p[u]))));
        g[u] = fmaf(wv.x, dv.x, fmaf(wv.y, dv.y, fmaf(wv.z, dv.z, fmaf(wv.w, dv.w, g[u]))));
      }
    }
    float* a2s = (float*)(sm + A2S_OFF);
    float* d2s = (float*)(sm + D2S_OFF);
#pragma unroll
    for (int u = 0; u < 8; ++u) {
      const int row = w8 + u * 8;
      float a = sigm(p[u] + sB2[o]);
      a2s[row * 68 + o] = a;
      d2s[row * 68 + o] = a * (1.f - a) * g[u];
    }
  }
  __syncthreads();

  // ---- S1: stage W3 (enc), dec W2 ----
  {
    float* W3s = (float*)(sm + W3S_OFF);
    float* W2d = (float*)(sm + W2D_OFF);
    for (int i = t; i < 2048; i += 512) W3s[(i >> 6) * 68 + (i & 63)] = W3[i];
    for (int i = t; i < 2048; i += 512) W2d[(i >> 5) * 36 + (i & 31)] = dW2[i];
  }
  __syncthreads();

  // ---- Phase C: enc layer 3 (32 outs, k=64) ----
  {
    const int o = t & 31, g16 = t >> 5;  // rows g16 + u*16
    const float4* W3f = (const float4*)(sm + W3S_OFF);
    const float4* a2f = (const float4*)(sm + A2S_OFF);
    const float4* d2f = (const float4*)(sm + D2S_OFF);
    float p[4], g[4];
#pragma unroll
    for (int u = 0; u < 4; ++u) { p[u] = 0.f; g[u] = 0.f; }
    for (int k4 = 0; k4 < 16; ++k4) {
      float4 wv = W3f[o * 17 + k4];
#pragma unroll
      for (int u = 0; u < 4; ++u) {
        float4 av = a2f[(g16 + u * 16) * 17 + k4];
        float4 dv = d2f[(g16 + u * 16) * 17 + k4];
        p[u] = fmaf(wv.x, av.x, fmaf(wv.y, av.y, fmaf(wv.z, av.z, fmaf(wv.w, av.w, p[u]))));
        g[u] = fmaf(wv.x, dv.x, fmaf(wv.y, dv.y, fmaf(wv.z, dv.z, fmaf(wv.w, dv.w, g[u]))));
      }
    }
    float* a3s = (float*)(sm + A3S_OFF);
    float* d3s = (float*)(sm + D3S_OFF);
#pragma unroll
    for (int u = 0; u < 4; ++u) {
      const int row = g16 + u * 16;
      float a = sigm(p[u] + sB3[o]);
      a3s[row * 36 + o] = a;
      d3s[row * 36 + o] = a * (1.f - a) * g[u];
    }
  }
  __syncthreads();

  // ---- S2 + Phase D: stage dec W3; enc layer 4 -> z ----
  {
    float* W3d = (float*)(sm + W3D_OFF);
    for (int i = t; i < 8192; i += 512) W3d[(i >> 6) * 68 + (i & 63)] = dW3[i];
    if (t < 192) {
      const int r = t / 3, j = t % 3;
      const float* a3s = (const float*)(sm + A3S_OFF);
      const float* d3s = (const float*)(sm + D3S_OFF);
      float p = 0.f, g = 0.f;
#pragma unroll
      for (int k = 0; k < 32; ++k) {
        float wv = W4s[j * 32 + k];
        p = fmaf(wv, a3s[r * 36 + k], p);
        g = fmaf(wv, d3s[r * 36 + k], g);
      }
      float zv = p + sB4[j];
      zs [r * 3 + j] = zv;
      zds[r * 3 + j] = g;
      z_out[(size_t)(r0 + r) * 3 + j] = zv;
    }
  }
  __syncthreads();

  // ---- Phase D2: sindy losses + zp; wave-0 reduce -> pe ----
  if (t < 64) {
    const int r = t;
    float s = zs[r * 3 + 0], d = zs[r * 3 + 1], tt = zs[r * 3 + 2];
    float th[7] = {1.f, s, s * s, s * d, s * tt, s * s * d, s * s * tt};
    float sz = 0.f;
#pragma unroll
    for (int j = 0; j < 3; ++j) {
      float zpv = 0.f;
#pragma unroll
      for (int i = 0; i < 7; ++i) zpv = fmaf(th[i], sC[i * 3 + j], zpv);
      zp[r * 3 + j] = zpv;
      float e = zds[r * 3 + j] - zpv;
      sz += e * e;
    }
    float e0 = s - size_in[r0 + r];
    float logit = tt;
    float trv = tr[r0 + r];
    float lt = fmaxf(logit, 0.f) + log1pf(expf(-fabsf(logit))) - logit * trv;
    float v0 = e0 * e0, v1 = lt, v2 = sz;
#pragma unroll
    for (int off = 32; off > 0; off >>= 1) {
      v0 += __shfl_down(v0, off);
      v1 += __shfl_down(v1, off);
      v2 += __shfl_down(v2, off);
    }
    if (t == 0) { pe0[blockIdx.x] = v0; pe1[blockIdx.x] = v1; pe2[blockIdx.x] = v2; }
  }
  __syncthreads();

  // ---- Phase E: dec layer 1 (32 outs, k=3) ----
  {
    const int o = t & 31, g16 = t >> 5;
    float* h1s = (float*)(sm + H1S_OFF);
    float* g1s = (float*)(sm + G1S_OFF);
#pragma unroll
    for (int u = 0; u < 4; ++u) {
      const int row = g16 + u * 16;
      float pp = sB1d[o], gg = 0.f;
#pragma unroll
      for (int k = 0; k < 3; ++k) {
        float wv = zW1[o * 3 + k];
        pp = fmaf(wv, zs[row * 3 + k], pp);
        gg = fmaf(wv, zp[row * 3 + k], gg);
      }
      float h = sigm(pp);
      h1s[row * 36 + o] = h;
      g1s[row * 36 + o] = h * (1.f - h) * gg;
    }
  }
  __syncthreads();

  // ---- Phase F: dec layer 2 (64 outs, k=32) ----
  {
    const int o = t & 63, w8 = t >> 6;
    const float4* W2df = (const float4*)(sm + W2D_OFF);
    const float4* h1f  = (const float4*)(sm + H1S_OFF);
    const float4* g1f  = (const float4*)(sm + G1S_OFF);
    float p[8], g[8];
#pragma unroll
    for (int u = 0; u < 8; ++u) { p[u] = sB2d[o]; g[u] = 0.f; }
    for (int k4 = 0; k4 < 8; ++k4) {
      float4 wv = W2df[o * 9 + k4];
#pragma unroll
      for (int u = 0; u < 8; ++u) {
        float4 av = h1f[(w8 + u * 8) * 9 + k4];
        float4 dv = g1f[(w8 + u * 8) * 9 + k4];
        p[u] = fmaf(wv.x, av.x, fmaf(wv.y, av.y, fmaf(wv.z, av.z, fmaf(wv.w, av.w, p[u]))));
        g[u] = fmaf(wv.x, dv.x, fmaf(wv.y, dv.y, fmaf(wv.z, dv.z, fmaf(wv.w, dv.w, g[u]))));
      }
    }
    float* h2s = (float*)(sm + H2S_OFF);
    float* g2s = (float*)(sm + G2S_OFF);
#pragma unroll
    for (int u = 0; u < 8; ++u) {
      const int row = w8 + u * 8;
      float h = sigm(p[u]);
      h2s[row * 68 + o] = h;
      g2s[row * 68 + o] = h * (1.f - h) * g[u];
    }
  }
  __syncthreads();

  // ---- Phase G: dec layer 3 (128 outs, k=64) -> h3b/g3b (bf16, global) ----
  {
    const int o = t & 127, g4 = t >> 7;   // rows g4 + u*4
    const float4* W3df = (const float4*)(sm + W3D_OFF);
    const float4* h2f  = (const float4*)(sm + H2S_OFF);
    const float4* g2f  = (const float4*)(sm + G2S_OFF);
    float p[16], g[16];
#pragma unroll
    for (int u = 0; u < 16; ++u) { p[u] = sB3d[o]; g[u] = 0.f; }
    for (int k4 = 0; k4 < 16; ++k4) {
      float4 wv = W3df[o * 17 + k4];
#pragma unroll
      for (int u = 0; u < 16; ++u) {
        float4 av = h2f[(g4 + u * 4) * 17 + k4];
        float4 dv = g2f[(g4 + u * 4) * 17 + k4];
        p[u] = fmaf(wv.x, av.x, fmaf(wv.y, av.y, fmaf(wv.z, av.z, fmaf(wv.w, av.w, p[u]))));
        g[u] = fmaf(wv.x, dv.x, fmaf(wv.y, dv.y, fmaf(wv.z, dv.z, fmaf(wv.w, dv.w, g[u]))));
      }
    }
#pragma unroll
    for (int u = 0; u < 16; ++u) {
      const int row = g4 + u * 4;
      float h = sigm(p[u]);
      h3b[(size_t)(r0 + row) * 128 + o] = f2b(h);
      g3b[(size_t)(r0 + row) * 128 + o] = f2b(h * (1.f - h) * g[u]);
    }
  }
}

// ---------------------------------------------------------------------------
// K4: dec4 (unchanged from r6/r7).
// ---------------------------------------------------------------------------
__global__ __launch_bounds__(256, 2) void dec4_mfma(
    const unsigned short* __restrict__ h3b, const unsigned short* __restrict__ g3b,
    const unsigned short* __restrict__ Wb, const float* __restrict__ bias,
    const float* __restrict__ x, const float* __restrict__ xd,
    float* __restrict__ xhat, float* __restrict__ pr, float* __restrict__ ps)
{
  __shared__ __align__(16) char Wsm[2][16384];
  __shared__ float sH[32 * 132];
  __shared__ float sG[32 * 132];
  __shared__ float red[8];
  const int t = threadIdx.x, w = t >> 6, L = t & 63, q = L >> 4, ln = L & 15;
  const int r0 = blockIdx.x * 32;

  short8 fh[2][4], fg[2][4];
  {
    const size_t a0 = (size_t)(r0 + ln) * 128;
    const size_t a1 = (size_t)(r0 + 16 + ln) * 128;
#pragma unroll
    for (int ks = 0; ks < 4; ++ks) {
      const int kb = ks * 32 + q * 8;
      fh[0][ks] = *(const short8*)&h3b[a0 + kb];
      fh[1][ks] = *(const short8*)&h3b[a1 + kb];
      fg[0][ks] = *(const short8*)&g3b[a0 + kb];
      fg[1][ks] = *(const short8*)&g3b[a1 + kb];
    }
  }

  const int srow0 = t >> 3;
  const int sch   = t & 7;
#define WSTAGE(buf, c_, kh_) { \
    char* dst = Wsm[buf] + (w << 10); \
    _Pragma("unroll") \
    for (int i = 0; i < 4; ++i) { \
      const int row_ = i * 32 + srow0; \
      const unsigned short* src_ = Wb + (((size_t)(c_) * 128 + row_) << 7) + (kh_) * 64 + ((sch ^ (row_ & 7)) << 3); \
      gload16(src_, dst + i * 4096); \
    } }

#define WFRAG(buf, ksl, n_) \
    (*(const short8*)(Wsm[buf] + ((w * 32 + (n_) * 16 + ln) << 7) + ((((ksl) * 4 + q) ^ (ln & 7)) << 4)))

  f32x4 accH[2][2], accG[2][2];
  const int erow = t >> 3;
  const int colb = (t & 7) * 4;
  const size_t ebase0 = (size_t)(r0 + erow) * 2048 + colb;

  WSTAGE(0, 0, 0)
  WSTAGE(1, 0, 1)
  float4 exC[4], edC[4], exN[4], edN[4];
#pragma unroll
  for (int j = 0; j < 4; ++j) {
    exC[j] = *(const float4*)&x [ebase0 + j * 32];
    edC[j] = *(const float4*)&xd[ebase0 + j * 32];
  }
  __syncthreads();

  float rsum = 0.f, ssum = 0.f;
  for (int c = 0; c < 16; ++c) {
#pragma unroll
    for (int m = 0; m < 2; ++m)
#pragma unroll
      for (int n = 0; n < 2; ++n) {
        accH[m][n] = (f32x4){0.f, 0.f, 0.f, 0.f};
        accG[m][n] = (f32x4){0.f, 0.f, 0.f, 0.f};
      }
#pragma unroll
    for (int ksl = 0; ksl < 2; ++ksl) {
      short8 bw0 = WFRAG(0, ksl, 0);
      short8 bw1 = WFRAG(0, ksl, 1);
      accH[0][0] = __builtin_amdgcn_mfma_f32_16x16x32_bf16(fh[0][ksl], bw0, accH[0][0], 0, 0, 0);
      accH[0][1] = __builtin_amdgcn_mfma_f32_16x16x32_bf16(fh[0][ksl], bw1, accH[0][1], 0, 0, 0);
      accH[1][0] = __builtin_amdgcn_mfma_f32_16x16x32_bf16(fh[1][ksl], bw0, accH[1][0], 0, 0, 0);
      accH[1][1] = __builtin_amdgcn_mfma_f32_16x16x32_bf16(fh[1][ksl], bw1, accH[1][1], 0, 0, 0);
      accG[0][0] = __builtin_amdgcn_mfma_f32_16x16x32_bf16(fg[0][ksl], bw0, accG[0][0], 0, 0, 0);
      accG[0][1] = __builtin_amdgcn_mfma_f32_16x16x32_bf16(fg[0][ksl], bw1, accG[0][1], 0, 0, 0);
      accG[1][0] = __builtin_amdgcn_mfma_f32_16x16x32_bf16(fg[1][ksl], bw0, accG[1][0], 0, 0, 0);
      accG[1][1] = __builtin_amdgcn_mfma_f32_16x16x32_bf16(fg[1][ksl], bw1, accG[1][1], 0, 0, 0);
    }
    __syncthreads();
    if (c < 15) {
      WSTAGE(0, c + 1, 0)
#pragma unroll
      for (int j = 0; j < 4; ++j) {
        exN[j] = *(const float4*)&x [ebase0 + (c + 1) * 128 + j * 32];
        edN[j] = *(const float4*)&xd[ebase0 + (c + 1) * 128 + j * 32];
      }
    }
#pragma unroll
    for (int ksl = 0; ksl < 2; ++ksl) {
      short8 bw0 = WFRAG(1, ksl, 0);
      short8 bw1 = WFRAG(1, ksl, 1);
      accH[0][0] = __builtin_amdgcn_mfma_f32_16x16x32_bf16(fh[0][2 + ksl], bw0, accH[0][0], 0, 0, 0);
      accH[0][1] = __builtin_amdgcn_mfma_f32_16x16x32_bf16(fh[0][2 + ksl], bw1, accH[0][1], 0, 0, 0);
      accH[1][0] = __builtin_amdgcn_mfma_f32_16x16x32_bf16(fh[1][2 + ksl], bw0, accH[1][0], 0, 0, 0);
      accH[1][1] = __builtin_amdgcn_mfma_f32_16x16x32_bf16(fh[1][2 + ksl], bw1, accH[1][1], 0, 0, 0);
      accG[0][0] = __builtin_amdgcn_mfma_f32_16x16x32_bf16(fg[0][2 + ksl], bw0, accG[0][0], 0, 0, 0);
      accG[0][1] = __builtin_amdgcn_mfma_f32_16x16x32_bf16(fg[0][2 + ksl], bw1, accG[0][1], 0, 0, 0);
      accG[1][0] = __builtin_amdgcn_mfma_f32_16x16x32_bf16(fg[1][2 + ksl], bw0, accG[1][0], 0, 0, 0);
      accG[1][1] = __builtin_amdgcn_mfma_f32_16x16x32_bf16(fg[1][2 + ksl], bw1, accG[1][1], 0, 0, 0);
    }
#pragma unroll
    for (int m = 0; m < 2; ++m)
#pragma unroll
      for (int n = 0; n < 2; ++n)
#pragma unroll
        for (int r = 0; r < 4; ++r) {
          const int rr = m * 16 + q * 4 + r;
          const int cc = w * 32 + n * 16 + ln;
          sH[rr * 132 + cc] = accH[m][n][r];
          sG[rr * 132 + cc] = accG[m][n][r];
        }
    __syncthreads();
    if (c < 15) WSTAGE(1, c + 1, 1)
    {
      const size_t gb = ebase0 + (size_t)c * 128;
#pragma unroll
      for (int j = 0; j < 4; ++j) {
        const int cc = colb + j * 32;
        float4 hv = *(const float4*)&sH[erow * 132 + cc];
        float4 gv = *(const float4*)&sG[erow * 132 + cc];
        float4 bv = *(const float4*)&bias[c * 128 + cc];
        f32x4 xh = {hv.x + bv.x, hv.y + bv.y, hv.z + bv.z, hv.w + bv.w};
        __builtin_nontemporal_store(xh, (f32x4*)&xhat[gb + j * 32]);
        float e;
        e = exC[j].x - xh[0]; rsum = fmaf(e, e, rsum);
        e = exC[j].y - xh[1]; rsum = fmaf(e, e, rsum);
        e = exC[j].z - xh[2]; rsum = fmaf(e, e, rsum);
        e = exC[j].w - xh[3]; rsum = fmaf(e, e, rsum);
        e = edC[j].x - gv.x; ssum = fmaf(e, e, ssum);
        e = edC[j].y - gv.y; ssum = fmaf(e, e, ssum);
        e = edC[j].z - gv.z; ssum = fmaf(e, e, ssum);
        e = edC[j].w - gv.w; ssum = fmaf(e, e, ssum);
      }
    }
#pragma unroll
    for (int j = 0; j < 4; ++j) { exC[j] = exN[j]; edC[j] = edN[j]; }
    __syncthreads();
  }
#undef WSTAGE
#undef WFRAG

#pragma unroll
  for (int off = 32; off > 0; off >>= 1) {
    rsum += __shfl_down(rsum, off);
    ssum += __shfl_down(ssum, off);
  }
  if (L == 0) { red[w * 2] = rsum; red[w * 2 + 1] = ssum; }
  __syncthreads();
  if (t == 0) {
    pr[blockIdx.x] = red[0] + red[2] + red[4] + red[6];
    ps[blockIdx.x] = red[1] + red[3] + red[5] + red[7];
  }
}

// ---------------------------------------------------------------------------
// K5: reduce all partials + write the 6 scalar outputs. pe*: 256; pr/ps: 512.
// ---------------------------------------------------------------------------
__global__ __launch_bounds__(256) void finalize_kernel(
    const float* __restrict__ pr, const float* __restrict__ ps,
    const float* __restrict__ pe0, const float* __restrict__ pe1,
    const float* __restrict__ pe2, const float* __restrict__ coef,
    float* __restrict__ outp)
{
  __shared__ float sred[4][5];
  const int t = threadIdx.x, L = t & 63, w = t >> 6;
  float s[5] = {0.f, 0.f, 0.f, 0.f, 0.f};
  if (t < 128) {                           // pr/ps: 512 floats each
    float4 a = *(const float4*)&pr[t * 4];
    float4 b = *(const float4*)&ps[t * 4];
    s[0] += a.x + a.y + a.z + a.w;
    s[1] += b.x + b.y + b.z + b.w;
  }
  if (t < 64) {                            // pe*: 256 floats each
    float4 a = *(const float4*)&pe0[t * 4];
    float4 b = *(const float4*)&pe1[t * 4];
    float4 c = *(const float4*)&pe2[t * 4];
    s[2] += a.x + a.y + a.z + a.w;
    s[3] += b.x + b.y + b.z + b.w;
    s[4] += c.x + c.y + c.z + c.w;
  }
#pragma unroll
  for (int off = 32; off > 0; off >>= 1)
#pragma unroll
    for (int k = 0; k < 5; ++k) s[k] += __shfl_down(s[k], off);
  if (L == 0)
#pragma unroll
    for (int k = 0; k < 5; ++k) sred[w][k] = s[k];
  __syncthreads();
  if (t == 0) {
    float r[5];
#pragma unroll
    for (int k = 0; k < 5; ++k)
      r[k] = sred[0][k] + sred[1][k] + sred[2][k] + sred[3][k];
    outp[0] = r[2] * (1.0f / 16384.0f);      // loss_po
    outp[1] = r[3] * (1.0f / 16384.0f);      // loss_tr
    outp[2] = r[0] * (1.0f / 33554432.0f);   // recon
    outp[3] = r[1] * (1.0f / 33554432.0f);   // sindy_x
    outp[4] = r[4] * (1.0f / 49152.0f);      // sindy_z
    float l1 = 0.f;
    for (int i = 0; i < 21; ++i) l1 += fabsf(coef[i]);
    outp[5] = l1 * (1.0f / 21.0f);
  }
}

extern "C" void kernel_launch(void* const* d_in, const int* in_sizes, int n_in,
                              void* d_out, int out_size, void* d_ws, size_t ws_size,
                              hipStream_t stream) {
  (void)in_sizes; (void)n_in; (void)out_size; (void)ws_size;
  const float* x    = (const float*)d_in[0];
  const float* xd   = (const float*)d_in[1];
  const float* tr   = (const float*)d_in[2];
  const float* sz   = (const float*)d_in[3];
  const float* eW1  = (const float*)d_in[4];
  const float* eb1  = (const float*)d_in[5];
  const float* eW2  = (const float*)d_in[6];
  const float* eb2  = (const float*)d_in[7];
  const float* eW3  = (const float*)d_in[8];
  const float* eb3  = (const float*)d_in[9];
  const float* eW4  = (const float*)d_in[10];
  const float* eb4  = (const float*)d_in[11];
  const float* dW1  = (const float*)d_in[12];
  const float* db1  = (const float*)d_in[13];
  const float* dW2  = (const float*)d_in[14];
  const float* db2  = (const float*)d_in[15];
  const float* dW3  = (const float*)d_in[16];
  const float* db3  = (const float*)d_in[17];
  const float* dW4  = (const float*)d_in[18];
  const float* db4  = (const float*)d_in[19];
  const float* coef = (const float*)d_in[20];

  float* ws = (float*)d_ws;
  unsigned short* h3b = (unsigned short*)(ws + 4243472);  // 2097152 bf16
  unsigned short* g3b = (unsigned short*)(ws + 5292048);  // 2097152 bf16
  unsigned short* Wb1 = (unsigned short*)(ws + 6340624);  // 262144 bf16
  unsigned short* Wb4 = (unsigned short*)(ws + 6471696);  // 262144 bf16
  float* pr  = ws + 6603024;                              // 512 f32
  float* ps  = ws + 6603536;                              // 512 f32
  float* pe0 = ws + 6604048;                              // 256 f32
  float* pe1 = ws + 6604304;                              // 256 f32
  float* pe2 = ws + 6604560;                              // 256 f32

  float* z_out = (float*)d_out;                           // 16384*3
  float* xhat  = (float*)d_out + 49152;                   // 16384*2048
  float* scal  = (float*)d_out + 49152 + 33554432;        // 6 scalars

  wcvt_kernel<<<1024, 256, 0, stream>>>(eW1, dW4, Wb1, Wb4);
  fused_enc<<<256, 512, 0, stream>>>(x, xd, tr, Wb1, eW1, eb1,
                                     eW2, eb2, eW3, eb3, eW4, eb4,
                                     coef, sz, dW1, db1, dW2, db2, dW3, db3,
                                     z_out, h3b, g3b, pe0, pe1, pe2);
  dec4_mfma<<<512, 256, 0, stream>>>(h3b, g3b, Wb4, db4, x, xd, xhat, pr, ps);
  finalize_kernel<<<1, 256, 0, stream>>>(pr, ps, pe0, pe1, pe2, coef, scal);
}